// Round 1
// baseline (5111.206 us; speedup 1.0000x reference)
//
#include <hip/hip_runtime.h>
#include <hip/hip_bf16.h>
#include <cmath>

// Problem sizes (fixed by the reference)
#define LSEQ 256
#define BB   128
#define DD   2048
#define HH   2048
#define LB   (LSEQ * BB)   // 32768 rows of the input-projection GEMM
#define BH   (BB * HH)     // 262144 elements of one timestep's state

typedef __attribute__((ext_vector_type(8))) short bf16x8;  // 8 bf16 (4 VGPRs)
typedef __attribute__((ext_vector_type(4))) float f32x4;   // MFMA accumulator

// Split an fp32 value into hi/lo bf16 (truncation split). 3-product MFMA
// (hi*hi + hi*lo + lo*hi) then gives ~2^-16 relative precision.
__device__ __forceinline__ void split2(float x, short& hi, short& lo) {
    unsigned u = __float_as_uint(x);
    hi = (short)(u >> 16);
    float r = x - __uint_as_float(u & 0xffff0000u);
    lo = (short)(__float_as_uint(r) >> 16);
}

// ---------------------------------------------------------------------------
// Kernel 1: xp = X[32768,2048] @ W_ih[2048,2048] + b   -> written into d_out
// Tile 128x128, 256 threads = 4 waves (2x2), each wave 64x64 = 4x4 16x16 frags.
// fp32 staged in LDS, split to bf16 hi/lo at fragment-read time.
// MFMA 16x16x32, C/D layout: row = 4*(lane>>4)+r, col = lane&15 (m89-verified).
// ---------------------------------------------------------------------------
__global__ __launch_bounds__(256) void xp_gemm(const float* __restrict__ A,
                                               const float* __restrict__ W,
                                               const float* __restrict__ bias,
                                               float* __restrict__ C) {
    __shared__ float As[128][33];  // [m][k], +1 pad breaks bank aliasing
    __shared__ float Bs[128][33];  // [n][k] (B staged transposed)

    const int tid  = threadIdx.x;
    const int lane = tid & 63;
    const int wave = tid >> 6;
    const int wm   = (wave >> 1) * 64;   // wave row offset in tile
    const int wn   = (wave & 1) * 64;    // wave col offset in tile
    const int l15  = lane & 15;
    const int lk   = (lane >> 4) * 8;    // k offset of this lane's fragment

    const int row0 = blockIdx.x * 128;   // 256 row tiles
    const int col0 = blockIdx.y * 128;   // 16 col tiles

    f32x4 acc[4][4] = {};

    // staging coords
    const int ar  = tid >> 3;        // 0..31
    const int ac4 = (tid & 7) * 4;   // 0..28
    const int bk  = tid >> 5;        // 0..7
    const int bc4 = (tid & 31) * 4;  // 0..124

    for (int k0 = 0; k0 < DD; k0 += 32) {
        // stage A tile: 128 rows x 32 k (coalesced float4)
#pragma unroll
        for (int i = 0; i < 4; ++i) {
            const float4 v = *reinterpret_cast<const float4*>(
                &A[(size_t)(row0 + ar + 32 * i) * DD + k0 + ac4]);
            As[ar + 32 * i][ac4 + 0] = v.x;
            As[ar + 32 * i][ac4 + 1] = v.y;
            As[ar + 32 * i][ac4 + 2] = v.z;
            As[ar + 32 * i][ac4 + 3] = v.w;
        }
        // stage B tile transposed: W rows k0..k0+32, cols col0..col0+128
#pragma unroll
        for (int i = 0; i < 4; ++i) {
            const float4 v = *reinterpret_cast<const float4*>(
                &W[(size_t)(k0 + bk + 8 * i) * HH + col0 + bc4]);
            Bs[bc4 + 0][bk + 8 * i] = v.x;
            Bs[bc4 + 1][bk + 8 * i] = v.y;
            Bs[bc4 + 2][bk + 8 * i] = v.z;
            Bs[bc4 + 3][bk + 8 * i] = v.w;
        }
        __syncthreads();

        // fragments: A row = l&15, k = 8*(l>>4)+j ; B col = l&15, same k
        bf16x8 ah[4], al[4], bh[4], bl[4];
#pragma unroll
        for (int m = 0; m < 4; ++m) {
            const float* p = &As[wm + m * 16 + l15][lk];
#pragma unroll
            for (int j = 0; j < 8; ++j) {
                short h, l;
                split2(p[j], h, l);
                ah[m][j] = h; al[m][j] = l;
            }
        }
#pragma unroll
        for (int n = 0; n < 4; ++n) {
            const float* p = &Bs[wn + n * 16 + l15][lk];
#pragma unroll
            for (int j = 0; j < 8; ++j) {
                short h, l;
                split2(p[j], h, l);
                bh[n][j] = h; bl[n][j] = l;
            }
        }
#pragma unroll
        for (int m = 0; m < 4; ++m)
#pragma unroll
            for (int n = 0; n < 4; ++n) {
                acc[m][n] = __builtin_amdgcn_mfma_f32_16x16x32_bf16(ah[m], bh[n], acc[m][n], 0, 0, 0);
                acc[m][n] = __builtin_amdgcn_mfma_f32_16x16x32_bf16(ah[m], bl[n], acc[m][n], 0, 0, 0);
                acc[m][n] = __builtin_amdgcn_mfma_f32_16x16x32_bf16(al[m], bh[n], acc[m][n], 0, 0, 0);
            }
        __syncthreads();
    }

    // epilogue: add bias, write fp32
    const int r4 = (lane >> 4) * 4;
#pragma unroll
    for (int m = 0; m < 4; ++m)
#pragma unroll
        for (int n = 0; n < 4; ++n)
#pragma unroll
            for (int r = 0; r < 4; ++r) {
                const int row = row0 + wm + m * 16 + r4 + r;
                const int col = col0 + wn + n * 16 + l15;
                C[(size_t)row * HH + col] = acc[m][n][r] + bias[col];
            }
}

// ---------------------------------------------------------------------------
// Kernel 2: t=0 step is just tanh(xp[0]) since h0 = 0.  In-place on outputs[0].
// ---------------------------------------------------------------------------
__global__ __launch_bounds__(256) void tanh0_kernel(float* __restrict__ out0) {
    const int i = blockIdx.x * 256 + threadIdx.x;  // 65536 float4 = 262144 elems
    float4* p = reinterpret_cast<float4*>(out0) + i;
    float4 v = *p;
    v.x = tanhf(v.x);
    v.y = tanhf(v.y);
    v.z = tanhf(v.z);
    v.w = tanhf(v.w);
    *p = v;
}

// ---------------------------------------------------------------------------
// Kernel 3: one scan step:  io = tanh(io + hprev @ W_hh)   (io holds xp[t])
// Tile 32x32, grid 256 blocks (blockIdx = mr*64 + nc so each XCD's round-robin
// block set re-reads the same 8 W-column slices -> W stays L2-resident).
// 4 waves split K (512 each), private LDS staging, LDS reduce at the end.
// ---------------------------------------------------------------------------
__global__ __launch_bounds__(256) void rnn_step(const float* __restrict__ hprev,
                                                const float* __restrict__ W,
                                                float* __restrict__ io) {
    __shared__ float As[4][32][33];
    __shared__ float Bs[4][32][33];
    __shared__ float red[4][32][33];

    const int tid  = threadIdx.x;
    const int lane = tid & 63;
    const int wave = tid >> 6;
    const int l15  = lane & 15;
    const int lk   = (lane >> 4) * 8;

    const int nc = blockIdx.x & 63;
    const int mr = blockIdx.x >> 6;
    const int m0 = mr * 32;
    const int n0 = nc * 32;

    const int r0 = lane >> 3;        // 0..7
    const int c4 = (lane & 7) * 4;   // 0..28

    f32x4 acc[2][2] = {};

    for (int kt = 0; kt < 16; ++kt) {
        const int k0 = wave * 512 + kt * 32;
        // stage A (h rows), wave-private
#pragma unroll
        for (int i = 0; i < 4; ++i) {
            const float4 v = *reinterpret_cast<const float4*>(
                &hprev[(size_t)(m0 + r0 + 8 * i) * HH + k0 + c4]);
            As[wave][r0 + 8 * i][c4 + 0] = v.x;
            As[wave][r0 + 8 * i][c4 + 1] = v.y;
            As[wave][r0 + 8 * i][c4 + 2] = v.z;
            As[wave][r0 + 8 * i][c4 + 3] = v.w;
        }
        // stage B transposed (W_hh slice), wave-private
#pragma unroll
        for (int i = 0; i < 4; ++i) {
            const float4 v = *reinterpret_cast<const float4*>(
                &W[(size_t)(k0 + r0 + 8 * i) * HH + n0 + c4]);
            Bs[wave][c4 + 0][r0 + 8 * i] = v.x;
            Bs[wave][c4 + 1][r0 + 8 * i] = v.y;
            Bs[wave][c4 + 2][r0 + 8 * i] = v.z;
            Bs[wave][c4 + 3][r0 + 8 * i] = v.w;
        }
        // wave-private LDS: compiler orders ds_write->ds_read, no barrier needed
        bf16x8 ah[2], al[2], bh[2], bl[2];
#pragma unroll
        for (int m = 0; m < 2; ++m) {
            const float* p = &As[wave][m * 16 + l15][lk];
#pragma unroll
            for (int j = 0; j < 8; ++j) {
                short h, l;
                split2(p[j], h, l);
                ah[m][j] = h; al[m][j] = l;
            }
        }
#pragma unroll
        for (int n = 0; n < 2; ++n) {
            const float* p = &Bs[wave][n * 16 + l15][lk];
#pragma unroll
            for (int j = 0; j < 8; ++j) {
                short h, l;
                split2(p[j], h, l);
                bh[n][j] = h; bl[n][j] = l;
            }
        }
#pragma unroll
        for (int m = 0; m < 2; ++m)
#pragma unroll
            for (int n = 0; n < 2; ++n) {
                acc[m][n] = __builtin_amdgcn_mfma_f32_16x16x32_bf16(ah[m], bh[n], acc[m][n], 0, 0, 0);
                acc[m][n] = __builtin_amdgcn_mfma_f32_16x16x32_bf16(ah[m], bl[n], acc[m][n], 0, 0, 0);
                acc[m][n] = __builtin_amdgcn_mfma_f32_16x16x32_bf16(al[m], bh[n], acc[m][n], 0, 0, 0);
            }
    }

    // per-wave partial -> LDS
    const int r4 = (lane >> 4) * 4;
#pragma unroll
    for (int m = 0; m < 2; ++m)
#pragma unroll
        for (int n = 0; n < 2; ++n)
#pragma unroll
            for (int r = 0; r < 4; ++r)
                red[wave][m * 16 + r4 + r][n * 16 + l15] = acc[m][n][r];
    __syncthreads();

    // reduce across waves + add xp (in io) + tanh + write back in place
    const int rr = tid >> 3;         // 0..31
    const int cc = (tid & 7) * 4;    // 0..28
    float* dst = &io[(size_t)(m0 + rr) * HH + n0 + cc];
    float4 xv = *reinterpret_cast<const float4*>(dst);
    float o0 = xv.x + red[0][rr][cc + 0] + red[1][rr][cc + 0] + red[2][rr][cc + 0] + red[3][rr][cc + 0];
    float o1 = xv.y + red[0][rr][cc + 1] + red[1][rr][cc + 1] + red[2][rr][cc + 1] + red[3][rr][cc + 1];
    float o2 = xv.z + red[0][rr][cc + 2] + red[1][rr][cc + 2] + red[2][rr][cc + 2] + red[3][rr][cc + 2];
    float o3 = xv.w + red[0][rr][cc + 3] + red[1][rr][cc + 3] + red[2][rr][cc + 3] + red[3][rr][cc + 3];
    float4 ov;
    ov.x = tanhf(o0);
    ov.y = tanhf(o1);
    ov.z = tanhf(o2);
    ov.w = tanhf(o3);
    *reinterpret_cast<float4*>(dst) = ov;
}

// ---------------------------------------------------------------------------
extern "C" void kernel_launch(void* const* d_in, const int* in_sizes, int n_in,
                              void* d_out, int out_size, void* d_ws, size_t ws_size,
                              hipStream_t stream) {
    (void)in_sizes; (void)n_in; (void)d_ws; (void)ws_size; (void)out_size;

    const float* X   = (const float*)d_in[0];  // [L,B,D]
    const float* Wih = (const float*)d_in[1];  // [D,H]
    const float* Whh = (const float*)d_in[2];  // [H,H]
    const float* b   = (const float*)d_in[3];  // [H]
    float* out = (float*)d_out;                // [L*B*H outputs][B*H final]

    // 1) xp = X @ W_ih + b  -> outputs region (in-place workspace for the scan)
    dim3 g1(LB / 128, HH / 128);
    xp_gemm<<<g1, 256, 0, stream>>>(X, Wih, b, out);

    // 2) t = 0: h = tanh(xp[0])
    tanh0_kernel<<<256, 256, 0, stream>>>(out);

    // 3) t = 1..255: h_t = tanh(xp[t] + h_{t-1} @ W_hh), in place
    for (int t = 1; t < LSEQ; ++t) {
        rnn_step<<<256, 256, 0, stream>>>(out + (size_t)(t - 1) * BH, Whh,
                                          out + (size_t)t * BH);
    }

    // 4) final state = outputs[L-1]
    hipMemcpyAsync(out + (size_t)LSEQ * BH, out + (size_t)(LSEQ - 1) * BH,
                   (size_t)BH * sizeof(float), hipMemcpyDeviceToDevice, stream);
}